// Round 4
// baseline (1552.612 us; speedup 1.0000x reference)
//
#include <hip/hip_runtime.h>
#include <math.h>

#define OBSD   256
#define TSEQ   4096
#define NBATCH 32
#define DMODEL 128
#define DSTATE 64
#define DINNER 256
#define NHEADS 4
#define HEADDIM 64
#define NPROJ  644
#define NTOK   (NBATCH*TSEQ)
#define CHUNK  128
#define NCHUNK (TSEQ/CHUNK)
#define NACT   64

// column offsets inside a zxbcdt row
#define ZC   0
#define XC   256
#define BCOL 512
#define CCOL 576
#define DTC  640

__device__ __forceinline__ float siluf(float x) { return x / (1.f + __expf(-x)); }

// ---------------------------------------------------------------------------
// fp32 tiled GEMM, A(MxK) row-major with row stride lda, B(KxN) row-major,
// C(MxN) row-major.  C = (A@B) * rowscale[r] + bias[c]  (either may be null)
// ---------------------------------------------------------------------------
template<int BM, int BN, int BK>
__launch_bounds__(256)
__global__ void gemm_rrr(const float* __restrict__ A, const float* __restrict__ B,
                         float* __restrict__ C, int M, int N, int K, int lda,
                         const float* __restrict__ bias, const float* __restrict__ rowscale)
{
    static_assert(BM == 128 && BN == 64 && BK == 16, "tile fixed");
    __shared__ float As[BK][BM + 4];
    __shared__ float Bs[BK][BN];
    const int tid = threadIdx.x;
    const int m0 = blockIdx.y * BM;
    const int n0 = blockIdx.x * BN;
    const int ty = tid >> 4;
    const int tx = tid & 15;

    float acc[8][4];
#pragma unroll
    for (int i = 0; i < 8; ++i)
#pragma unroll
        for (int j = 0; j < 4; ++j) acc[i][j] = 0.f;

    for (int k0 = 0; k0 < K; k0 += BK) {
#pragma unroll
        for (int l = 0; l < 2; ++l) {
            const int idx = tid + l * 256;
            const int r  = idx >> 2;
            const int c4 = (idx & 3) << 2;
            const float4 v = *(const float4*)(A + (size_t)(m0 + r) * lda + k0 + c4);
            As[c4 + 0][r] = v.x; As[c4 + 1][r] = v.y;
            As[c4 + 2][r] = v.z; As[c4 + 3][r] = v.w;
        }
        {
            const int r  = tid >> 4;
            const int c4 = (tid & 15) << 2;
            const int n  = n0 + c4;
            float4 v;
            if (n + 3 < N) {
                v = *(const float4*)(B + (size_t)(k0 + r) * N + n);
            } else {
                v.x = (n + 0) < N ? B[(size_t)(k0 + r) * N + n + 0] : 0.f;
                v.y = (n + 1) < N ? B[(size_t)(k0 + r) * N + n + 1] : 0.f;
                v.z = (n + 2) < N ? B[(size_t)(k0 + r) * N + n + 2] : 0.f;
                v.w = (n + 3) < N ? B[(size_t)(k0 + r) * N + n + 3] : 0.f;
            }
            *(float4*)&Bs[r][c4] = v;
        }
        __syncthreads();
#pragma unroll
        for (int kk = 0; kk < BK; ++kk) {
            const float4 a0 = *(const float4*)&As[kk][ty * 8];
            const float4 a1 = *(const float4*)&As[kk][ty * 8 + 4];
            const float4 b0 = *(const float4*)&Bs[kk][tx * 4];
            const float a[8] = {a0.x, a0.y, a0.z, a0.w, a1.x, a1.y, a1.z, a1.w};
            const float bb[4] = {b0.x, b0.y, b0.z, b0.w};
#pragma unroll
            for (int i = 0; i < 8; ++i)
#pragma unroll
                for (int j = 0; j < 4; ++j)
                    acc[i][j] = fmaf(a[i], bb[j], acc[i][j]);
        }
        __syncthreads();
    }

#pragma unroll
    for (int i = 0; i < 8; ++i) {
        const int r = m0 + ty * 8 + i;
        const float rs = rowscale ? rowscale[r] : 1.f;
        const int c = n0 + tx * 4;
        if (c + 3 < N) {
            float4 v;
            v.x = acc[i][0] * rs + (bias ? bias[c + 0] : 0.f);
            v.y = acc[i][1] * rs + (bias ? bias[c + 1] : 0.f);
            v.z = acc[i][2] * rs + (bias ? bias[c + 2] : 0.f);
            v.w = acc[i][3] * rs + (bias ? bias[c + 3] : 0.f);
            *(float4*)(C + (size_t)r * N + c) = v;
        } else {
#pragma unroll
            for (int j = 0; j < 4; ++j)
                if (c + j < N)
                    C[(size_t)r * N + c + j] = acc[i][j] * rs + (bias ? bias[c + j] : 0.f);
        }
    }
}

// ---------------------------------------------------------------------------
__global__ void fuse_whead(const float* __restrict__ W_out, const float* __restrict__ W_act,
                           const float* __restrict__ W_val, const float* __restrict__ norm_w,
                           float* __restrict__ Wh, float* __restrict__ Wv)
{
    const int k = blockIdx.x;
    const int j = threadIdx.x;
    float s = 0.f;
    for (int m = 0; m < DMODEL; ++m)
        s = fmaf(W_out[k * DMODEL + m], W_act[m * NACT + j], s);
    Wh[k * NACT + j] = s * norm_w[k];
    if (j == 0) {
        float sv = 0.f;
        for (int m = 0; m < DMODEL; ++m)
            sv = fmaf(W_out[k * DMODEL + m], W_val[m], sv);
        Wv[k] = sv * norm_w[k];
    }
}

// ---------------------------------------------------------------------------
__global__ void prep_dt(const float* __restrict__ zx, const float* __restrict__ dt_bias,
                        const float* __restrict__ A_log,
                        float* __restrict__ dtbuf, float* __restrict__ dAbuf)
{
    const int idx = blockIdx.x * 256 + threadIdx.x;   // tok*4 + h
    if (idx >= NTOK * NHEADS) return;
    const int tok = idx >> 2;
    const int h = idx & 3;
    const float x = zx[(size_t)tok * NPROJ + DTC + h] + dt_bias[h];
    const float dt = (x > 20.f) ? x : log1pf(expf(x));
    const float A = -expf(A_log[h]);
    dtbuf[idx] = dt;
    dAbuf[idx] = expf(dt * A);
}

// ---------------------------------------------------------------------------
// Chunked selective scan. Block = (chunk, batch), 256 threads = 4 waves,
// wave h handles head h, lane p holds state row s[p][0..63] in registers.
// Conv(4)+SiLU fused: B/C during LDS staging, x via rolling register window.
// FINAL=false: phase 1 -> per-chunk states from zero + dA products (B only).
// FINAL=true : phase 3 -> y, g = y*silu(z), rms per token, value head (B+C).
//   g is written INTO the z-column slots of zxbcdt (stride NPROJ): each z
//   element is read exactly once by the thread that then overwrites it, and
//   each block owns its token rows exclusively -> no cross-block hazard.
//   (zx/g intentionally NOT __restrict__ because they alias.)
// ---------------------------------------------------------------------------
template<bool FINAL>
__launch_bounds__(256, 4)
__global__ void scan_kernel(const float* zx,
                            const float* __restrict__ dtbuf,
                            const float* __restrict__ dAbuf,
                            const float* __restrict__ W_conv,
                            const float* __restrict__ b_conv,
                            const float* __restrict__ Dparam,
                            float* __restrict__ states,   // [b*4+h][chunk][64][64]
                            float* __restrict__ dAprod,   // [b*4+h][chunk]
                            float* g,                     // alias of zxbcdt (z cols)
                            float* __restrict__ rmsbuf,   // [tok]
                            const float* __restrict__ Wv, // [256]
                            const float* __restrict__ bval,
                            float* __restrict__ values)   // [tok]
{
    const int b   = blockIdx.y;
    const int ch  = blockIdx.x;
    const int tid = threadIdx.x;
    const int h = tid >> 6;
    const int p = tid & 63;

    constexpr int NCH = FINAL ? 4 : 2;         // phase 3 stages B+C, phase 1 only B
    constexpr int BCW = NCH * 32;              // 128 (FINAL) / 64
    __shared__ float sBC[2][8][BCW];
    __shared__ float red[2][8][NHEADS][2];

    const int xch = h * HEADDIM + p;
    const float wcx0 = W_conv[xch * 4 + 0], wcx1 = W_conv[xch * 4 + 1];
    const float wcx2 = W_conv[xch * 4 + 2], wcx3 = W_conv[xch * 4 + 3];
    const float bcx = b_conv[xch];
    const float Dh = Dparam[h];
    const float wvp = FINAL ? Wv[xch] : 0.f;

    // staging role: thread -> (step si, NCH conv channels at scb)
    const int si  = tid >> 5;                  // 0..7
    const int scb = (tid & 31) * NCH;
    float swc[NCH][4], sbcv[NCH];
#pragma unroll
    for (int j = 0; j < NCH; ++j) {
        sbcv[j] = b_conv[DINNER + scb + j];
#pragma unroll
        for (int k = 0; k < 4; ++k) swc[j][k] = W_conv[(DINNER + scb + j) * 4 + k];
    }

    const size_t row0 = (size_t)b * TSEQ;
    const int tbase = ch * CHUNK;

    float s[64];
    const int bh = b * NHEADS + h;
    const size_t stoff = (((size_t)bh * NCHUNK + ch) * 64 + p) * 64;
    if constexpr (FINAL) {
#pragma unroll
        for (int n4 = 0; n4 < 16; ++n4) {
            const float4 v = *(const float4*)(states + stoff + n4 * 4);
            s[n4 * 4 + 0] = v.x; s[n4 * 4 + 1] = v.y; s[n4 * 4 + 2] = v.z; s[n4 * 4 + 3] = v.w;
        }
    } else {
#pragma unroll
        for (int n = 0; n < 64; ++n) s[n] = 0.f;
    }

    // rolling raw-x window (t-3, t-2, t-1)
    float xw0 = 0.f, xw1 = 0.f, xw2 = 0.f;
    if (tbase >= 1) xw2 = zx[(row0 + tbase - 1) * NPROJ + XC + xch];
    if (tbase >= 2) xw1 = zx[(row0 + tbase - 2) * NPROJ + XC + xch];
    if (tbase >= 3) xw0 = zx[(row0 + tbase - 3) * NPROJ + XC + xch];

    float dAp = 1.f;

    auto stage = [&](int tl, int bufi) {
        const int t = tbase + tl * 8 + si;
        float a[NCH];
#pragma unroll
        for (int j = 0; j < NCH; ++j) a[j] = sbcv[j];
#pragma unroll
        for (int k = 0; k < 4; ++k) {
            const int tt = t - 3 + k;
            if (tt >= 0) {
                const float* src = zx + (row0 + tt) * NPROJ + BCOL + scb;
                if constexpr (FINAL) {
                    const float4 rv = *(const float4*)src;
                    a[0] = fmaf(rv.x, swc[0][k], a[0]);
                    a[1] = fmaf(rv.y, swc[1][k], a[1]);
                    a[2] = fmaf(rv.z, swc[2][k], a[2]);
                    a[3] = fmaf(rv.w, swc[3][k], a[3]);
                } else {
                    const float2 rv = *(const float2*)src;
                    a[0] = fmaf(rv.x, swc[0][k], a[0]);
                    a[1] = fmaf(rv.y, swc[1][k], a[1]);
                }
            }
        }
#pragma unroll
        for (int j = 0; j < NCH; ++j)
            sBC[bufi][si][scb + j] = siluf(a[j]);
    };

    auto consume = [&](int tl, int bufi) {
#pragma unroll
        for (int i = 0; i < 8; ++i) {
            const int t = tbase + tl * 8 + i;
            const size_t tok = row0 + t;
            const float dt = dtbuf[tok * NHEADS + h];
            const float dA = dAbuf[tok * NHEADS + h];
            const float xw3 = zx[tok * NPROJ + XC + xch];
            float xc = fmaf(xw3, wcx3, fmaf(xw2, wcx2, fmaf(xw1, wcx1, fmaf(xw0, wcx0, bcx))));
            xc = siluf(xc);
            xw0 = xw1; xw1 = xw2; xw2 = xw3;
            const float dtx = dt * xc;
            if constexpr (!FINAL) {
                dAp *= dA;
#pragma unroll
                for (int n4 = 0; n4 < 16; ++n4) {
                    const float4 Bv = *(const float4*)&sBC[bufi][i][n4 * 4];
                    s[n4 * 4 + 0] = fmaf(dA, s[n4 * 4 + 0], dtx * Bv.x);
                    s[n4 * 4 + 1] = fmaf(dA, s[n4 * 4 + 1], dtx * Bv.y);
                    s[n4 * 4 + 2] = fmaf(dA, s[n4 * 4 + 2], dtx * Bv.z);
                    s[n4 * 4 + 3] = fmaf(dA, s[n4 * 4 + 3], dtx * Bv.w);
                }
            } else {
                float y0 = 0.f, y1 = 0.f, y2 = 0.f, y3 = 0.f;
#pragma unroll
                for (int n4 = 0; n4 < 16; ++n4) {
                    const float4 Bv = *(const float4*)&sBC[bufi][i][n4 * 4];
                    const float4 Cv = *(const float4*)&sBC[bufi][i][64 + n4 * 4];
                    const float s0_ = fmaf(dA, s[n4 * 4 + 0], dtx * Bv.x); s[n4 * 4 + 0] = s0_;
                    const float s1_ = fmaf(dA, s[n4 * 4 + 1], dtx * Bv.y); s[n4 * 4 + 1] = s1_;
                    const float s2_ = fmaf(dA, s[n4 * 4 + 2], dtx * Bv.z); s[n4 * 4 + 2] = s2_;
                    const float s3_ = fmaf(dA, s[n4 * 4 + 3], dtx * Bv.w); s[n4 * 4 + 3] = s3_;
                    y0 = fmaf(s0_, Cv.x, y0);
                    y1 = fmaf(s1_, Cv.y, y1);
                    y2 = fmaf(s2_, Cv.z, y2);
                    y3 = fmaf(s3_, Cv.w, y3);
                }
                const float y = (y0 + y1) + (y2 + y3) + Dh * xc;
                const float z = zx[tok * NPROJ + ZC + xch];
                const float gv = y * siluf(z);
                g[tok * NPROJ + ZC + xch] = gv;   // overwrite z slot (read above)
                float ssq = gv * gv;
                float gw = gv * wvp;
#pragma unroll
                for (int d = 1; d < 64; d <<= 1) {
                    ssq += __shfl_xor(ssq, d, 64);
                    gw  += __shfl_xor(gw, d, 64);
                }
                if (p == 0) { red[bufi][i][h][0] = ssq; red[bufi][i][h][1] = gw; }
            }
        }
    };

    stage(0, 0);
    __syncthreads();
    for (int tl = 0; tl < CHUNK / 8; ++tl) {
        const int bufi = tl & 1;
        if (tl + 1 < CHUNK / 8) stage(tl + 1, bufi ^ 1);
        consume(tl, bufi);
        __syncthreads();
        if constexpr (FINAL) {
            if (tid < 8) {
                const size_t tok = row0 + tbase + tl * 8 + tid;
                const float ssq = red[bufi][tid][0][0] + red[bufi][tid][1][0]
                                + red[bufi][tid][2][0] + red[bufi][tid][3][0];
                const float gw  = red[bufi][tid][0][1] + red[bufi][tid][1][1]
                                + red[bufi][tid][2][1] + red[bufi][tid][3][1];
                const float rms = rsqrtf(ssq * (1.f / DINNER) + 1e-5f);
                rmsbuf[tok] = rms;
                values[tok] = gw * rms + bval[0];
            }
        }
    }

    if constexpr (!FINAL) {
#pragma unroll
        for (int n4 = 0; n4 < 16; ++n4)
            *(float4*)(states + stoff + n4 * 4) =
                make_float4(s[n4 * 4 + 0], s[n4 * 4 + 1], s[n4 * 4 + 2], s[n4 * 4 + 3]);
        if (p == 0) dAprod[bh * NCHUNK + ch] = dAp;
    }
}

// ---------------------------------------------------------------------------
// Inter-chunk state recurrence (in place): one thread per (bh, state element).
// states[bh][c][elem] becomes the INITIAL state of chunk c.
// grid: 128 bh * 16 blocks, 256 threads -> elem 0..4095 per bh. Coalesced.
// ---------------------------------------------------------------------------
__global__ void chunk_scan(float* __restrict__ states, const float* __restrict__ dAprod)
{
    __shared__ float sdA[NCHUNK];
    const int bh = blockIdx.x >> 4;                       // 16 blocks per bh
    const int elem = ((blockIdx.x & 15) << 8) | threadIdx.x;
    if (threadIdx.x < NCHUNK) sdA[threadIdx.x] = dAprod[bh * NCHUNK + threadIdx.x];
    __syncthreads();
    const size_t base = (size_t)bh * NCHUNK * 4096 + elem;
    float s0 = 0.f;
    for (int c = 0; c < NCHUNK; ++c) {
        const size_t off = base + (size_t)c * 4096;
        const float Sc = states[off];
        states[off] = s0;
        s0 = fmaf(sdA[c], s0, Sc);
    }
}

// ---------------------------------------------------------------------------
extern "C" void kernel_launch(void* const* d_in, const int* in_sizes, int n_in,
                              void* d_out, int out_size, void* d_ws, size_t ws_size,
                              hipStream_t stream)
{
    (void)in_sizes; (void)n_in; (void)out_size; (void)ws_size;
    const float* obs     = (const float*)d_in[0];
    const float* W_enc   = (const float*)d_in[1];
    const float* b_enc   = (const float*)d_in[2];
    const float* W_in    = (const float*)d_in[3];
    const float* W_conv  = (const float*)d_in[4];
    const float* b_conv  = (const float*)d_in[5];
    const float* dt_bias = (const float*)d_in[6];
    const float* A_log   = (const float*)d_in[7];
    const float* Dp      = (const float*)d_in[8];
    const float* norm_w  = (const float*)d_in[9];
    const float* W_out   = (const float*)d_in[10];
    const float* W_act   = (const float*)d_in[11];
    const float* b_act   = (const float*)d_in[12];
    const float* W_val   = (const float*)d_in[13];
    const float* b_val   = (const float*)d_in[14];

    float* logits = (float*)d_out;
    float* values = logits + (size_t)NTOK * NACT;

    char* ws = (char*)d_ws;
    size_t off = 0;
    auto alloc = [&](size_t nfloats) {
        float* ptr = (float*)(ws + off);
        off += ((nfloats * 4 + 255) / 256) * 256;
        return ptr;
    };
    // ws high-water: 337.6 + 67.1 + 67.1 + ~5 MB  = ~477 MB (round-2's 510 MB passed)
    float* zxbcdt = alloc((size_t)NTOK * NPROJ);                    // 337.6 MB
    float* hidden = alloc((size_t)NTOK * DMODEL);                   // 67.1 MB
    float* states = alloc((size_t)NBATCH * NHEADS * NCHUNK * 4096); // 67.1 MB
    float* dAp    = alloc(NBATCH * NHEADS * NCHUNK);
    float* dtbuf  = alloc((size_t)NTOK * NHEADS);
    float* dAbuf  = alloc((size_t)NTOK * NHEADS);
    float* rmsbuf = alloc(NTOK);
    float* Wh     = alloc(DINNER * NACT);
    float* Wv     = alloc(DINNER);

    // 1. fused head weights
    fuse_whead<<<DINNER, NACT, 0, stream>>>(W_out, W_act, W_val, norm_w, Wh, Wv);
    // 2. hidden = obs @ W_enc + b_enc
    gemm_rrr<128, 64, 16><<<dim3(DMODEL / 64, NTOK / 128), 256, 0, stream>>>(
        obs, W_enc, hidden, NTOK, DMODEL, OBSD, OBSD, b_enc, nullptr);
    // 3. zxbcdt = hidden @ W_in
    gemm_rrr<128, 64, 16><<<dim3((NPROJ + 63) / 64, NTOK / 128), 256, 0, stream>>>(
        hidden, W_in, zxbcdt, NTOK, NPROJ, DMODEL, DMODEL, nullptr, nullptr);
    // 4. dt / dA
    prep_dt<<<(NTOK * NHEADS + 255) / 256, 256, 0, stream>>>(zxbcdt, dt_bias, A_log, dtbuf, dAbuf);
    // 5. phase 1: chunk states
    scan_kernel<false><<<dim3(NCHUNK, NBATCH), 256, 0, stream>>>(
        zxbcdt, dtbuf, dAbuf, W_conv, b_conv, Dp, states, dAp,
        nullptr, nullptr, nullptr, nullptr, nullptr);
    // 6. phase 2: inter-chunk recurrence
    chunk_scan<<<NBATCH * NHEADS * 16, 256, 0, stream>>>(states, dAp);
    // 7. phase 3: outputs (g -> z slots of zxbcdt, rms, values)
    scan_kernel<true><<<dim3(NCHUNK, NBATCH), 256, 0, stream>>>(
        zxbcdt, dtbuf, dAbuf, W_conv, b_conv, Dp, states, dAp,
        zxbcdt, rmsbuf, Wv, b_val, values);
    // 8. logits = rms * (g @ Wh) + b_act   (A = z-cols of zxbcdt, lda = NPROJ)
    gemm_rrr<128, 64, 16><<<dim3(1, NTOK / 128), 256, 0, stream>>>(
        zxbcdt, Wh, logits, NTOK, NACT, DINNER, NPROJ, b_act, rmsbuf);
}

// Round 5
// 1176.012 us; speedup vs baseline: 1.3202x; 1.3202x over previous
//
#include <hip/hip_runtime.h>
#include <math.h>

#define OBSD   256
#define TSEQ   4096
#define NBATCH 32
#define DMODEL 128
#define DSTATE 64
#define DINNER 256
#define NHEADS 4
#define HEADDIM 64
#define NPROJ  644
#define NTOK   (NBATCH*TSEQ)
#define CHUNK  128
#define NCHUNK (TSEQ/CHUNK)
#define NACT   64

// column offsets inside a zxbcdt row
#define ZC   0
#define XC   256
#define BCOL 512
#define CCOL 576
#define DTC  640

__device__ __forceinline__ float siluf(float x) { return x / (1.f + __expf(-x)); }

// ---------------------------------------------------------------------------
// fp32 tiled GEMM, A(MxK) row-major with row stride lda, B(KxN) row-major,
// C(MxN) row-major.  C = (A@B) * rowscale[r] + bias[c]  (either may be null)
// ---------------------------------------------------------------------------
template<int BM, int BN, int BK>
__launch_bounds__(256)
__global__ void gemm_rrr(const float* __restrict__ A, const float* __restrict__ B,
                         float* __restrict__ C, int M, int N, int K, int lda,
                         const float* __restrict__ bias, const float* __restrict__ rowscale)
{
    static_assert(BM == 128 && BN == 64 && BK == 16, "tile fixed");
    __shared__ float As[BK][BM + 4];
    __shared__ float Bs[BK][BN];
    const int tid = threadIdx.x;
    const int m0 = blockIdx.y * BM;
    const int n0 = blockIdx.x * BN;
    const int ty = tid >> 4;
    const int tx = tid & 15;

    float acc[8][4];
#pragma unroll
    for (int i = 0; i < 8; ++i)
#pragma unroll
        for (int j = 0; j < 4; ++j) acc[i][j] = 0.f;

    for (int k0 = 0; k0 < K; k0 += BK) {
#pragma unroll
        for (int l = 0; l < 2; ++l) {
            const int idx = tid + l * 256;
            const int r  = idx >> 2;
            const int c4 = (idx & 3) << 2;
            const float4 v = *(const float4*)(A + (size_t)(m0 + r) * lda + k0 + c4);
            As[c4 + 0][r] = v.x; As[c4 + 1][r] = v.y;
            As[c4 + 2][r] = v.z; As[c4 + 3][r] = v.w;
        }
        {
            const int r  = tid >> 4;
            const int c4 = (tid & 15) << 2;
            const int n  = n0 + c4;
            float4 v;
            if (n + 3 < N) {
                v = *(const float4*)(B + (size_t)(k0 + r) * N + n);
            } else {
                v.x = (n + 0) < N ? B[(size_t)(k0 + r) * N + n + 0] : 0.f;
                v.y = (n + 1) < N ? B[(size_t)(k0 + r) * N + n + 1] : 0.f;
                v.z = (n + 2) < N ? B[(size_t)(k0 + r) * N + n + 2] : 0.f;
                v.w = (n + 3) < N ? B[(size_t)(k0 + r) * N + n + 3] : 0.f;
            }
            *(float4*)&Bs[r][c4] = v;
        }
        __syncthreads();
#pragma unroll
        for (int kk = 0; kk < BK; ++kk) {
            const float4 a0 = *(const float4*)&As[kk][ty * 8];
            const float4 a1 = *(const float4*)&As[kk][ty * 8 + 4];
            const float4 b0 = *(const float4*)&Bs[kk][tx * 4];
            const float a[8] = {a0.x, a0.y, a0.z, a0.w, a1.x, a1.y, a1.z, a1.w};
            const float bb[4] = {b0.x, b0.y, b0.z, b0.w};
#pragma unroll
            for (int i = 0; i < 8; ++i)
#pragma unroll
                for (int j = 0; j < 4; ++j)
                    acc[i][j] = fmaf(a[i], bb[j], acc[i][j]);
        }
        __syncthreads();
    }

#pragma unroll
    for (int i = 0; i < 8; ++i) {
        const int r = m0 + ty * 8 + i;
        const float rs = rowscale ? rowscale[r] : 1.f;
        const int c = n0 + tx * 4;
        if (c + 3 < N) {
            float4 v;
            v.x = acc[i][0] * rs + (bias ? bias[c + 0] : 0.f);
            v.y = acc[i][1] * rs + (bias ? bias[c + 1] : 0.f);
            v.z = acc[i][2] * rs + (bias ? bias[c + 2] : 0.f);
            v.w = acc[i][3] * rs + (bias ? bias[c + 3] : 0.f);
            *(float4*)(C + (size_t)r * N + c) = v;
        } else {
#pragma unroll
            for (int j = 0; j < 4; ++j)
                if (c + j < N)
                    C[(size_t)r * N + c + j] = acc[i][j] * rs + (bias ? bias[c + j] : 0.f);
        }
    }
}

// ---------------------------------------------------------------------------
__global__ void fuse_whead(const float* __restrict__ W_out, const float* __restrict__ W_act,
                           const float* __restrict__ W_val, const float* __restrict__ norm_w,
                           float* __restrict__ Wh, float* __restrict__ Wv)
{
    const int k = blockIdx.x;
    const int j = threadIdx.x;
    float s = 0.f;
    for (int m = 0; m < DMODEL; ++m)
        s = fmaf(W_out[k * DMODEL + m], W_act[m * NACT + j], s);
    Wh[k * NACT + j] = s * norm_w[k];
    if (j == 0) {
        float sv = 0.f;
        for (int m = 0; m < DMODEL; ++m)
            sv = fmaf(W_out[k * DMODEL + m], W_val[m], sv);
        Wv[k] = sv * norm_w[k];
    }
}

// ---------------------------------------------------------------------------
__global__ void prep_dt(const float* __restrict__ zx, const float* __restrict__ dt_bias,
                        const float* __restrict__ A_log,
                        float* __restrict__ dtbuf, float* __restrict__ dAbuf)
{
    const int idx = blockIdx.x * 256 + threadIdx.x;   // tok*4 + h
    if (idx >= NTOK * NHEADS) return;
    const int tok = idx >> 2;
    const int h = idx & 3;
    const float x = zx[(size_t)tok * NPROJ + DTC + h] + dt_bias[h];
    const float dt = (x > 20.f) ? x : log1pf(expf(x));
    const float A = -expf(A_log[h]);
    dtbuf[idx] = dt;
    dAbuf[idx] = expf(dt * A);
}

// ---------------------------------------------------------------------------
// Chunked selective scan. Block = (chunk, batch), 256 threads = 4 waves,
// wave h handles head h, lane p holds state row s[p][0..63] in registers.
// Conv(4)+SiLU fused: B/C during LDS staging, x via rolling register window.
// FINAL=false: phase 1 -> per-chunk states from zero + dA products (B only).
// FINAL=true : phase 3 -> y, g = y*silu(z), rms per token, value head (B+C).
//   g is written INTO the z-column slots of zxbcdt (stride NPROJ): each z
//   element is read exactly once by the thread that then overwrites it, and
//   each block owns its token rows exclusively -> no cross-block hazard.
//   (zx/g intentionally NOT __restrict__ because they alias.)
// NOTE: plain __launch_bounds__(256). The (256,4) variant capped VGPR at 64,
// spilling the 64-float state array to scratch (hbm_bytes 4.5x, 1553 us).
// VGPR=112 naturally supports 4 waves/SIMD with the 1024-block grid.
// ---------------------------------------------------------------------------
template<bool FINAL>
__launch_bounds__(256)
__global__ void scan_kernel(const float* zx,
                            const float* __restrict__ dtbuf,
                            const float* __restrict__ dAbuf,
                            const float* __restrict__ W_conv,
                            const float* __restrict__ b_conv,
                            const float* __restrict__ Dparam,
                            float* __restrict__ states,   // [b*4+h][chunk][64][64]
                            float* __restrict__ dAprod,   // [b*4+h][chunk]
                            float* g,                     // alias of zxbcdt (z cols)
                            float* __restrict__ rmsbuf,   // [tok]
                            const float* __restrict__ Wv, // [256]
                            const float* __restrict__ bval,
                            float* __restrict__ values)   // [tok]
{
    const int b   = blockIdx.y;
    const int ch  = blockIdx.x;
    const int tid = threadIdx.x;
    const int h = tid >> 6;
    const int p = tid & 63;

    constexpr int NCH = FINAL ? 4 : 2;         // phase 3 stages B+C, phase 1 only B
    constexpr int BCW = NCH * 32;              // 128 (FINAL) / 64
    __shared__ float sBC[2][8][BCW];
    __shared__ float red[2][8][NHEADS][2];

    const int xch = h * HEADDIM + p;
    const float wcx0 = W_conv[xch * 4 + 0], wcx1 = W_conv[xch * 4 + 1];
    const float wcx2 = W_conv[xch * 4 + 2], wcx3 = W_conv[xch * 4 + 3];
    const float bcx = b_conv[xch];
    const float Dh = Dparam[h];
    const float wvp = FINAL ? Wv[xch] : 0.f;

    // staging role: thread -> (step si, NCH conv channels at scb)
    const int si  = tid >> 5;                  // 0..7
    const int scb = (tid & 31) * NCH;
    float swc[NCH][4], sbcv[NCH];
#pragma unroll
    for (int j = 0; j < NCH; ++j) {
        sbcv[j] = b_conv[DINNER + scb + j];
#pragma unroll
        for (int k = 0; k < 4; ++k) swc[j][k] = W_conv[(DINNER + scb + j) * 4 + k];
    }

    const size_t row0 = (size_t)b * TSEQ;
    const int tbase = ch * CHUNK;

    float s[64];
    const int bh = b * NHEADS + h;
    const size_t stoff = (((size_t)bh * NCHUNK + ch) * 64 + p) * 64;
    if constexpr (FINAL) {
#pragma unroll
        for (int n4 = 0; n4 < 16; ++n4) {
            const float4 v = *(const float4*)(states + stoff + n4 * 4);
            s[n4 * 4 + 0] = v.x; s[n4 * 4 + 1] = v.y; s[n4 * 4 + 2] = v.z; s[n4 * 4 + 3] = v.w;
        }
    } else {
#pragma unroll
        for (int n = 0; n < 64; ++n) s[n] = 0.f;
    }

    // rolling raw-x window (t-3, t-2, t-1)
    float xw0 = 0.f, xw1 = 0.f, xw2 = 0.f;
    if (tbase >= 1) xw2 = zx[(row0 + tbase - 1) * NPROJ + XC + xch];
    if (tbase >= 2) xw1 = zx[(row0 + tbase - 2) * NPROJ + XC + xch];
    if (tbase >= 3) xw0 = zx[(row0 + tbase - 3) * NPROJ + XC + xch];

    float dAp = 1.f;

    auto stage = [&](int tl, int bufi) {
        const int t = tbase + tl * 8 + si;
        float a[NCH];
#pragma unroll
        for (int j = 0; j < NCH; ++j) a[j] = sbcv[j];
#pragma unroll
        for (int k = 0; k < 4; ++k) {
            const int tt = t - 3 + k;
            if (tt >= 0) {
                const float* src = zx + (row0 + tt) * NPROJ + BCOL + scb;
                if constexpr (FINAL) {
                    const float4 rv = *(const float4*)src;
                    a[0] = fmaf(rv.x, swc[0][k], a[0]);
                    a[1] = fmaf(rv.y, swc[1][k], a[1]);
                    a[2] = fmaf(rv.z, swc[2][k], a[2]);
                    a[3] = fmaf(rv.w, swc[3][k], a[3]);
                } else {
                    const float2 rv = *(const float2*)src;
                    a[0] = fmaf(rv.x, swc[0][k], a[0]);
                    a[1] = fmaf(rv.y, swc[1][k], a[1]);
                }
            }
        }
#pragma unroll
        for (int j = 0; j < NCH; ++j)
            sBC[bufi][si][scb + j] = siluf(a[j]);
    };

    auto consume = [&](int tl, int bufi) {
#pragma unroll
        for (int i = 0; i < 8; ++i) {
            const int t = tbase + tl * 8 + i;
            const size_t tok = row0 + t;
            const float dt = dtbuf[tok * NHEADS + h];
            const float dA = dAbuf[tok * NHEADS + h];
            const float xw3 = zx[tok * NPROJ + XC + xch];
            float xc = fmaf(xw3, wcx3, fmaf(xw2, wcx2, fmaf(xw1, wcx1, fmaf(xw0, wcx0, bcx))));
            xc = siluf(xc);
            xw0 = xw1; xw1 = xw2; xw2 = xw3;
            const float dtx = dt * xc;
            if constexpr (!FINAL) {
                dAp *= dA;
#pragma unroll
                for (int n4 = 0; n4 < 16; ++n4) {
                    const float4 Bv = *(const float4*)&sBC[bufi][i][n4 * 4];
                    s[n4 * 4 + 0] = fmaf(dA, s[n4 * 4 + 0], dtx * Bv.x);
                    s[n4 * 4 + 1] = fmaf(dA, s[n4 * 4 + 1], dtx * Bv.y);
                    s[n4 * 4 + 2] = fmaf(dA, s[n4 * 4 + 2], dtx * Bv.z);
                    s[n4 * 4 + 3] = fmaf(dA, s[n4 * 4 + 3], dtx * Bv.w);
                }
            } else {
                float y0 = 0.f, y1 = 0.f, y2 = 0.f, y3 = 0.f;
#pragma unroll
                for (int n4 = 0; n4 < 16; ++n4) {
                    const float4 Bv = *(const float4*)&sBC[bufi][i][n4 * 4];
                    const float4 Cv = *(const float4*)&sBC[bufi][i][64 + n4 * 4];
                    const float s0_ = fmaf(dA, s[n4 * 4 + 0], dtx * Bv.x); s[n4 * 4 + 0] = s0_;
                    const float s1_ = fmaf(dA, s[n4 * 4 + 1], dtx * Bv.y); s[n4 * 4 + 1] = s1_;
                    const float s2_ = fmaf(dA, s[n4 * 4 + 2], dtx * Bv.z); s[n4 * 4 + 2] = s2_;
                    const float s3_ = fmaf(dA, s[n4 * 4 + 3], dtx * Bv.w); s[n4 * 4 + 3] = s3_;
                    y0 = fmaf(s0_, Cv.x, y0);
                    y1 = fmaf(s1_, Cv.y, y1);
                    y2 = fmaf(s2_, Cv.z, y2);
                    y3 = fmaf(s3_, Cv.w, y3);
                }
                const float y = (y0 + y1) + (y2 + y3) + Dh * xc;
                const float z = zx[tok * NPROJ + ZC + xch];
                const float gv = y * siluf(z);
                g[tok * NPROJ + ZC + xch] = gv;   // overwrite z slot (read above)
                float ssq = gv * gv;
                float gw = gv * wvp;
#pragma unroll
                for (int d = 1; d < 64; d <<= 1) {
                    ssq += __shfl_xor(ssq, d, 64);
                    gw  += __shfl_xor(gw, d, 64);
                }
                if (p == 0) { red[bufi][i][h][0] = ssq; red[bufi][i][h][1] = gw; }
            }
        }
    };

    stage(0, 0);
    __syncthreads();
    for (int tl = 0; tl < CHUNK / 8; ++tl) {
        const int bufi = tl & 1;
        if (tl + 1 < CHUNK / 8) stage(tl + 1, bufi ^ 1);
        consume(tl, bufi);
        __syncthreads();
        if constexpr (FINAL) {
            if (tid < 8) {
                const size_t tok = row0 + tbase + tl * 8 + tid;
                const float ssq = red[bufi][tid][0][0] + red[bufi][tid][1][0]
                                + red[bufi][tid][2][0] + red[bufi][tid][3][0];
                const float gw  = red[bufi][tid][0][1] + red[bufi][tid][1][1]
                                + red[bufi][tid][2][1] + red[bufi][tid][3][1];
                const float rms = rsqrtf(ssq * (1.f / DINNER) + 1e-5f);
                rmsbuf[tok] = rms;
                values[tok] = gw * rms + bval[0];
            }
        }
    }

    if constexpr (!FINAL) {
#pragma unroll
        for (int n4 = 0; n4 < 16; ++n4)
            *(float4*)(states + stoff + n4 * 4) =
                make_float4(s[n4 * 4 + 0], s[n4 * 4 + 1], s[n4 * 4 + 2], s[n4 * 4 + 3]);
        if (p == 0) dAprod[bh * NCHUNK + ch] = dAp;
    }
}

// ---------------------------------------------------------------------------
// Inter-chunk state recurrence (in place): one thread per (bh, state element).
// states[bh][c][elem] becomes the INITIAL state of chunk c.
// grid: 128 bh * 16 blocks, 256 threads -> elem 0..4095 per bh. Coalesced.
// ---------------------------------------------------------------------------
__global__ void chunk_scan(float* __restrict__ states, const float* __restrict__ dAprod)
{
    __shared__ float sdA[NCHUNK];
    const int bh = blockIdx.x >> 4;                       // 16 blocks per bh
    const int elem = ((blockIdx.x & 15) << 8) | threadIdx.x;
    if (threadIdx.x < NCHUNK) sdA[threadIdx.x] = dAprod[bh * NCHUNK + threadIdx.x];
    __syncthreads();
    const size_t base = (size_t)bh * NCHUNK * 4096 + elem;
    float s0 = 0.f;
    for (int c = 0; c < NCHUNK; ++c) {
        const size_t off = base + (size_t)c * 4096;
        const float Sc = states[off];
        states[off] = s0;
        s0 = fmaf(sdA[c], s0, Sc);
    }
}

// ---------------------------------------------------------------------------
extern "C" void kernel_launch(void* const* d_in, const int* in_sizes, int n_in,
                              void* d_out, int out_size, void* d_ws, size_t ws_size,
                              hipStream_t stream)
{
    (void)in_sizes; (void)n_in; (void)out_size; (void)ws_size;
    const float* obs     = (const float*)d_in[0];
    const float* W_enc   = (const float*)d_in[1];
    const float* b_enc   = (const float*)d_in[2];
    const float* W_in    = (const float*)d_in[3];
    const float* W_conv  = (const float*)d_in[4];
    const float* b_conv  = (const float*)d_in[5];
    const float* dt_bias = (const float*)d_in[6];
    const float* A_log   = (const float*)d_in[7];
    const float* Dp      = (const float*)d_in[8];
    const float* norm_w  = (const float*)d_in[9];
    const float* W_out   = (const float*)d_in[10];
    const float* W_act   = (const float*)d_in[11];
    const float* b_act   = (const float*)d_in[12];
    const float* W_val   = (const float*)d_in[13];
    const float* b_val   = (const float*)d_in[14];

    float* logits = (float*)d_out;
    float* values = logits + (size_t)NTOK * NACT;

    char* ws = (char*)d_ws;
    size_t off = 0;
    auto alloc = [&](size_t nfloats) {
        float* ptr = (float*)(ws + off);
        off += ((nfloats * 4 + 255) / 256) * 256;
        return ptr;
    };
    // ws high-water: 337.6 + 67.1 + 67.1 + ~5 MB  = ~477 MB
    float* zxbcdt = alloc((size_t)NTOK * NPROJ);                    // 337.6 MB
    float* hidden = alloc((size_t)NTOK * DMODEL);                   // 67.1 MB
    float* states = alloc((size_t)NBATCH * NHEADS * NCHUNK * 4096); // 67.1 MB
    float* dAp    = alloc(NBATCH * NHEADS * NCHUNK);
    float* dtbuf  = alloc((size_t)NTOK * NHEADS);
    float* dAbuf  = alloc((size_t)NTOK * NHEADS);
    float* rmsbuf = alloc(NTOK);
    float* Wh     = alloc(DINNER * NACT);
    float* Wv     = alloc(DINNER);

    // 1. fused head weights
    fuse_whead<<<DINNER, NACT, 0, stream>>>(W_out, W_act, W_val, norm_w, Wh, Wv);
    // 2. hidden = obs @ W_enc + b_enc
    gemm_rrr<128, 64, 16><<<dim3(DMODEL / 64, NTOK / 128), 256, 0, stream>>>(
        obs, W_enc, hidden, NTOK, DMODEL, OBSD, OBSD, b_enc, nullptr);
    // 3. zxbcdt = hidden @ W_in
    gemm_rrr<128, 64, 16><<<dim3((NPROJ + 63) / 64, NTOK / 128), 256, 0, stream>>>(
        hidden, W_in, zxbcdt, NTOK, NPROJ, DMODEL, DMODEL, nullptr, nullptr);
    // 4. dt / dA
    prep_dt<<<(NTOK * NHEADS + 255) / 256, 256, 0, stream>>>(zxbcdt, dt_bias, A_log, dtbuf, dAbuf);
    // 5. phase 1: chunk states
    scan_kernel<false><<<dim3(NCHUNK, NBATCH), 256, 0, stream>>>(
        zxbcdt, dtbuf, dAbuf, W_conv, b_conv, Dp, states, dAp,
        nullptr, nullptr, nullptr, nullptr, nullptr);
    // 6. phase 2: inter-chunk recurrence
    chunk_scan<<<NBATCH * NHEADS * 16, 256, 0, stream>>>(states, dAp);
    // 7. phase 3: outputs (g -> z slots of zxbcdt, rms, values)
    scan_kernel<true><<<dim3(NCHUNK, NBATCH), 256, 0, stream>>>(
        zxbcdt, dtbuf, dAbuf, W_conv, b_conv, Dp, states, dAp,
        zxbcdt, rmsbuf, Wv, b_val, values);
    // 8. logits = rms * (g @ Wh) + b_act   (A = z-cols of zxbcdt, lda = NPROJ)
    gemm_rrr<128, 64, 16><<<dim3(1, NTOK / 128), 256, 0, stream>>>(
        zxbcdt, Wh, logits, NTOK, NACT, DINNER, NPROJ, b_act, rmsbuf);
}

// Round 7
// 1157.687 us; speedup vs baseline: 1.3411x; 1.0158x over previous
//
#include <hip/hip_runtime.h>
#include <math.h>

#define OBSD   256
#define TSEQ   4096
#define NBATCH 32
#define DMODEL 128
#define DSTATE 64
#define DINNER 256
#define NHEADS 4
#define HEADDIM 64
#define NPROJ  644
#define NTOK   (NBATCH*TSEQ)
#define CHUNK  128
#define NCHUNK (TSEQ/CHUNK)
#define NACT   64
#define BCW2   128   // bcbuf row width (B 64 | C 64)

__device__ __forceinline__ float siluf(float x) { return x / (1.f + __expf(-x)); }

// ---------------------------------------------------------------------------
// fp32 tiled GEMM, A(MxK) row-major with row stride lda, B(KxN) row-major,
// C(MxN) row-major.  C = (A@B) * rowscale[r] + bias[c]  (either may be null)
// ---------------------------------------------------------------------------
template<int BM, int BN, int BK>
__launch_bounds__(256)
__global__ void gemm_rrr(const float* __restrict__ A, const float* __restrict__ B,
                         float* __restrict__ C, int M, int N, int K, int lda,
                         const float* __restrict__ bias, const float* __restrict__ rowscale)
{
    static_assert(BM == 128 && BN == 64 && BK == 16, "tile fixed");
    __shared__ float As[BK][BM + 4];
    __shared__ float Bs[BK][BN];
    const int tid = threadIdx.x;
    const int m0 = blockIdx.y * BM;
    const int n0 = blockIdx.x * BN;
    const int ty = tid >> 4;
    const int tx = tid & 15;

    float acc[8][4];
#pragma unroll
    for (int i = 0; i < 8; ++i)
#pragma unroll
        for (int j = 0; j < 4; ++j) acc[i][j] = 0.f;

    for (int k0 = 0; k0 < K; k0 += BK) {
#pragma unroll
        for (int l = 0; l < 2; ++l) {
            const int idx = tid + l * 256;
            const int r  = idx >> 2;
            const int c4 = (idx & 3) << 2;
            const float4 v = *(const float4*)(A + (size_t)(m0 + r) * lda + k0 + c4);
            As[c4 + 0][r] = v.x; As[c4 + 1][r] = v.y;
            As[c4 + 2][r] = v.z; As[c4 + 3][r] = v.w;
        }
        {
            const int r  = tid >> 4;
            const int c4 = (tid & 15) << 2;
            const int n  = n0 + c4;
            float4 v;
            if (n + 3 < N) {
                v = *(const float4*)(B + (size_t)(k0 + r) * N + n);
            } else {
                v.x = (n + 0) < N ? B[(size_t)(k0 + r) * N + n + 0] : 0.f;
                v.y = (n + 1) < N ? B[(size_t)(k0 + r) * N + n + 1] : 0.f;
                v.z = (n + 2) < N ? B[(size_t)(k0 + r) * N + n + 2] : 0.f;
                v.w = (n + 3) < N ? B[(size_t)(k0 + r) * N + n + 3] : 0.f;
            }
            *(float4*)&Bs[r][c4] = v;
        }
        __syncthreads();
#pragma unroll
        for (int kk = 0; kk < BK; ++kk) {
            const float4 a0 = *(const float4*)&As[kk][ty * 8];
            const float4 a1 = *(const float4*)&As[kk][ty * 8 + 4];
            const float4 b0 = *(const float4*)&Bs[kk][tx * 4];
            const float a[8] = {a0.x, a0.y, a0.z, a0.w, a1.x, a1.y, a1.z, a1.w};
            const float bb[4] = {b0.x, b0.y, b0.z, b0.w};
#pragma unroll
            for (int i = 0; i < 8; ++i)
#pragma unroll
                for (int j = 0; j < 4; ++j)
                    acc[i][j] = fmaf(a[i], bb[j], acc[i][j]);
        }
        __syncthreads();
    }

#pragma unroll
    for (int i = 0; i < 8; ++i) {
        const int r = m0 + ty * 8 + i;
        const float rs = rowscale ? rowscale[r] : 1.f;
        const int c = n0 + tx * 4;
        if (c + 3 < N) {
            float4 v;
            v.x = acc[i][0] * rs + (bias ? bias[c + 0] : 0.f);
            v.y = acc[i][1] * rs + (bias ? bias[c + 1] : 0.f);
            v.z = acc[i][2] * rs + (bias ? bias[c + 2] : 0.f);
            v.w = acc[i][3] * rs + (bias ? bias[c + 3] : 0.f);
            *(float4*)(C + (size_t)r * N + c) = v;
        } else {
#pragma unroll
            for (int j = 0; j < 4; ++j)
                if (c + j < N)
                    C[(size_t)r * N + c + j] = acc[i][j] * rs + (bias ? bias[c + j] : 0.f);
        }
    }
}

// ---------------------------------------------------------------------------
// in_proj GEMM with SEGMENTED epilogue: output column c routed to dense
// buffers zbuf[.,256] | xbuf[.,256] | bcbuf[.,128] | dtcol[.,4].
// Tile width 64 aligns with all segment boundaries (256/512/640).
// ---------------------------------------------------------------------------
template<int BM, int BN, int BK>
__launch_bounds__(256)
__global__ void gemm_inproj(const float* __restrict__ A, const float* __restrict__ B,
                            int M, int N, int K, int lda,
                            float* __restrict__ zbuf, float* __restrict__ xbuf,
                            float* __restrict__ bcbuf, float* __restrict__ dtcol)
{
    static_assert(BM == 128 && BN == 64 && BK == 16, "tile fixed");
    __shared__ float As[BK][BM + 4];
    __shared__ float Bs[BK][BN];
    const int tid = threadIdx.x;
    const int m0 = blockIdx.y * BM;
    const int n0 = blockIdx.x * BN;
    const int ty = tid >> 4;
    const int tx = tid & 15;

    float acc[8][4];
#pragma unroll
    for (int i = 0; i < 8; ++i)
#pragma unroll
        for (int j = 0; j < 4; ++j) acc[i][j] = 0.f;

    for (int k0 = 0; k0 < K; k0 += BK) {
#pragma unroll
        for (int l = 0; l < 2; ++l) {
            const int idx = tid + l * 256;
            const int r  = idx >> 2;
            const int c4 = (idx & 3) << 2;
            const float4 v = *(const float4*)(A + (size_t)(m0 + r) * lda + k0 + c4);
            As[c4 + 0][r] = v.x; As[c4 + 1][r] = v.y;
            As[c4 + 2][r] = v.z; As[c4 + 3][r] = v.w;
        }
        {
            const int r  = tid >> 4;
            const int c4 = (tid & 15) << 2;
            const int n  = n0 + c4;
            float4 v;
            if (n + 3 < N) {
                v = *(const float4*)(B + (size_t)(k0 + r) * N + n);
            } else {
                v.x = (n + 0) < N ? B[(size_t)(k0 + r) * N + n + 0] : 0.f;
                v.y = (n + 1) < N ? B[(size_t)(k0 + r) * N + n + 1] : 0.f;
                v.z = (n + 2) < N ? B[(size_t)(k0 + r) * N + n + 2] : 0.f;
                v.w = (n + 3) < N ? B[(size_t)(k0 + r) * N + n + 3] : 0.f;
            }
            *(float4*)&Bs[r][c4] = v;
        }
        __syncthreads();
#pragma unroll
        for (int kk = 0; kk < BK; ++kk) {
            const float4 a0 = *(const float4*)&As[kk][ty * 8];
            const float4 a1 = *(const float4*)&As[kk][ty * 8 + 4];
            const float4 b0 = *(const float4*)&Bs[kk][tx * 4];
            const float a[8] = {a0.x, a0.y, a0.z, a0.w, a1.x, a1.y, a1.z, a1.w};
            const float bb[4] = {b0.x, b0.y, b0.z, b0.w};
#pragma unroll
            for (int i = 0; i < 8; ++i)
#pragma unroll
                for (int j = 0; j < 4; ++j)
                    acc[i][j] = fmaf(a[i], bb[j], acc[i][j]);
        }
        __syncthreads();
    }

    // segmented store (n0 uniform per block -> no divergence)
#pragma unroll
    for (int i = 0; i < 8; ++i) {
        const int r = m0 + ty * 8 + i;
        const int c = n0 + tx * 4;
        const float4 v = make_float4(acc[i][0], acc[i][1], acc[i][2], acc[i][3]);
        if (n0 < 256) {
            *(float4*)(zbuf + (size_t)r * DINNER + c) = v;
        } else if (n0 < 512) {
            *(float4*)(xbuf + (size_t)r * DINNER + (c - 256)) = v;
        } else if (n0 < 640) {
            *(float4*)(bcbuf + (size_t)r * BCW2 + (c - 512)) = v;
        } else {
            if (tx == 0) *(float4*)(dtcol + (size_t)r * 4) = v;  // cols 640..643
        }
    }
}

// ---------------------------------------------------------------------------
__global__ void fuse_whead(const float* __restrict__ W_out, const float* __restrict__ W_act,
                           const float* __restrict__ W_val, const float* __restrict__ norm_w,
                           float* __restrict__ Wh, float* __restrict__ Wv)
{
    const int k = blockIdx.x;
    const int j = threadIdx.x;
    float s = 0.f;
    for (int m = 0; m < DMODEL; ++m)
        s = fmaf(W_out[k * DMODEL + m], W_act[m * NACT + j], s);
    Wh[k * NACT + j] = s * norm_w[k];
    if (j == 0) {
        float sv = 0.f;
        for (int m = 0; m < DMODEL; ++m)
            sv = fmaf(W_out[k * DMODEL + m], W_val[m], sv);
        Wv[k] = sv * norm_w[k];
    }
}

// ---------------------------------------------------------------------------
__global__ void prep_dt(const float* __restrict__ dtcol, const float* __restrict__ dt_bias,
                        const float* __restrict__ A_log,
                        float* __restrict__ dtbuf, float* __restrict__ dAbuf)
{
    const int idx = blockIdx.x * 256 + threadIdx.x;   // tok*4 + h
    if (idx >= NTOK * NHEADS) return;
    const int h = idx & 3;
    const float x = dtcol[idx] + dt_bias[h];
    const float dt = (x > 20.f) ? x : log1pf(expf(x));
    const float A = -expf(A_log[h]);
    dtbuf[idx] = dt;
    dAbuf[idx] = expf(dt * A);
}

// ---------------------------------------------------------------------------
// Chunked selective scan over DENSE buffers. Block = (chunk, batch),
// 256 threads = 4 waves, wave h = head h, lane p holds state row s[p][0..63].
// Conv(4)+SiLU fused: B/C during LDS staging, x via rolling register window.
// FINAL=false: phase 1 -> per-chunk states from zero + dA products (B only).
// FINAL=true : phase 3 -> y, g = y*silu(z) written IN PLACE into zbuf
//   (each z element read once by the thread that overwrites it), rms, value.
// Plain __launch_bounds__(256): the (256,4) variant spilled the state array.
// ---------------------------------------------------------------------------
template<bool FINAL>
__launch_bounds__(256)
__global__ void scan_kernel(const float* __restrict__ xbuf,   // [tok][256]
                            const float* __restrict__ bcbuf,  // [tok][128]
                            float* zbuf,                      // [tok][256] z -> g in place
                            const float* __restrict__ dtbuf,
                            const float* __restrict__ dAbuf,
                            const float* __restrict__ W_conv,
                            const float* __restrict__ b_conv,
                            const float* __restrict__ Dparam,
                            float* __restrict__ states,   // [b*4+h][chunk][64][64]
                            float* __restrict__ dAprod,   // [b*4+h][chunk]
                            float* __restrict__ rmsbuf,   // [tok]
                            const float* __restrict__ Wv, // [256]
                            const float* __restrict__ bval,
                            float* __restrict__ values)   // [tok]
{
    const int b   = blockIdx.y;
    const int ch  = blockIdx.x;
    const int tid = threadIdx.x;
    const int h = tid >> 6;
    const int p = tid & 63;

    constexpr int NCH = FINAL ? 4 : 2;         // phase 3 stages B+C, phase 1 only B
    constexpr int BCW = NCH * 32;              // 128 (FINAL) / 64
    __shared__ float sBC[2][8][BCW];
    __shared__ float red[2][8][NHEADS][2];

    const int xch = h * HEADDIM + p;
    const float wcx0 = W_conv[xch * 4 + 0], wcx1 = W_conv[xch * 4 + 1];
    const float wcx2 = W_conv[xch * 4 + 2], wcx3 = W_conv[xch * 4 + 3];
    const float bcx = b_conv[xch];
    const float Dh = Dparam[h];
    const float wvp = FINAL ? Wv[xch] : 0.f;

    // staging role: thread -> (step si, NCH conv channels at scb)
    const int si  = tid >> 5;                  // 0..7
    const int scb = (tid & 31) * NCH;
    float swc[NCH][4], sbcv[NCH];
#pragma unroll
    for (int j = 0; j < NCH; ++j) {
        sbcv[j] = b_conv[DINNER + scb + j];
#pragma unroll
        for (int k = 0; k < 4; ++k) swc[j][k] = W_conv[(DINNER + scb + j) * 4 + k];
    }

    const size_t row0 = (size_t)b * TSEQ;
    const int tbase = ch * CHUNK;

    float s[64];
    const int bh = b * NHEADS + h;
    const size_t stoff = (((size_t)bh * NCHUNK + ch) * 64 + p) * 64;
    if constexpr (FINAL) {
#pragma unroll
        for (int n4 = 0; n4 < 16; ++n4) {
            const float4 v = *(const float4*)(states + stoff + n4 * 4);
            s[n4 * 4 + 0] = v.x; s[n4 * 4 + 1] = v.y; s[n4 * 4 + 2] = v.z; s[n4 * 4 + 3] = v.w;
        }
    } else {
#pragma unroll
        for (int n = 0; n < 64; ++n) s[n] = 0.f;
    }

    // rolling raw-x window (t-3, t-2, t-1)
    float xw0 = 0.f, xw1 = 0.f, xw2 = 0.f;
    if (tbase >= 1) xw2 = xbuf[(row0 + tbase - 1) * DINNER + xch];
    if (tbase >= 2) xw1 = xbuf[(row0 + tbase - 2) * DINNER + xch];
    if (tbase >= 3) xw0 = xbuf[(row0 + tbase - 3) * DINNER + xch];

    float dAp = 1.f;

    auto stage = [&](int tl, int bufi) {
        const int t = tbase + tl * 8 + si;
        float a[NCH];
#pragma unroll
        for (int j = 0; j < NCH; ++j) a[j] = sbcv[j];
#pragma unroll
        for (int k = 0; k < 4; ++k) {
            const int tt = t - 3 + k;
            if (tt >= 0) {
                const float* src = bcbuf + (row0 + tt) * BCW2 + scb;
                if constexpr (FINAL) {
                    const float4 rv = *(const float4*)src;
                    a[0] = fmaf(rv.x, swc[0][k], a[0]);
                    a[1] = fmaf(rv.y, swc[1][k], a[1]);
                    a[2] = fmaf(rv.z, swc[2][k], a[2]);
                    a[3] = fmaf(rv.w, swc[3][k], a[3]);
                } else {
                    const float2 rv = *(const float2*)src;
                    a[0] = fmaf(rv.x, swc[0][k], a[0]);
                    a[1] = fmaf(rv.y, swc[1][k], a[1]);
                }
            }
        }
#pragma unroll
        for (int j = 0; j < NCH; ++j)
            sBC[bufi][si][scb + j] = siluf(a[j]);
    };

    auto consume = [&](int tl, int bufi) {
#pragma unroll
        for (int i = 0; i < 8; ++i) {
            const int t = tbase + tl * 8 + i;
            const size_t tok = row0 + t;
            const float dt = dtbuf[tok * NHEADS + h];
            const float dA = dAbuf[tok * NHEADS + h];
            const float xw3 = xbuf[tok * DINNER + xch];
            float xc = fmaf(xw3, wcx3, fmaf(xw2, wcx2, fmaf(xw1, wcx1, fmaf(xw0, wcx0, bcx))));
            xc = siluf(xc);
            xw0 = xw1; xw1 = xw2; xw2 = xw3;
            const float dtx = dt * xc;
            if constexpr (!FINAL) {
                dAp *= dA;
#pragma unroll
                for (int n4 = 0; n4 < 16; ++n4) {
                    const float4 Bv = *(const float4*)&sBC[bufi][i][n4 * 4];
                    s[n4 * 4 + 0] = fmaf(dA, s[n4 * 4 + 0], dtx * Bv.x);
                    s[n4 * 4 + 1] = fmaf(dA, s[n4 * 4 + 1], dtx * Bv.y);
                    s[n4 * 4 + 2] = fmaf(dA, s[n4 * 4 + 2], dtx * Bv.z);
                    s[n4 * 4 + 3] = fmaf(dA, s[n4 * 4 + 3], dtx * Bv.w);
                }
            } else {
                float y0 = 0.f, y1 = 0.f, y2 = 0.f, y3 = 0.f;
#pragma unroll
                for (int n4 = 0; n4 < 16; ++n4) {
                    const float4 Bv = *(const float4*)&sBC[bufi][i][n4 * 4];
                    const float4 Cv = *(const float4*)&sBC[bufi][i][64 + n4 * 4];
                    const float s0_ = fmaf(dA, s[n4 * 4 + 0], dtx * Bv.x); s[n4 * 4 + 0] = s0_;
                    const float s1_ = fmaf(dA, s[n4 * 4 + 1], dtx * Bv.y); s[n4 * 4 + 1] = s1_;
                    const float s2_ = fmaf(dA, s[n4 * 4 + 2], dtx * Bv.z); s[n4 * 4 + 2] = s2_;
                    const float s3_ = fmaf(dA, s[n4 * 4 + 3], dtx * Bv.w); s[n4 * 4 + 3] = s3_;
                    y0 = fmaf(s0_, Cv.x, y0);
                    y1 = fmaf(s1_, Cv.y, y1);
                    y2 = fmaf(s2_, Cv.z, y2);
                    y3 = fmaf(s3_, Cv.w, y3);
                }
                const float y = (y0 + y1) + (y2 + y3) + Dh * xc;
                const float z = zbuf[tok * DINNER + xch];
                const float gv = y * siluf(z);
                zbuf[tok * DINNER + xch] = gv;    // overwrite z slot (read above)
                float ssq = gv * gv;
                float gw = gv * wvp;
#pragma unroll
                for (int d = 1; d < 64; d <<= 1) {
                    ssq += __shfl_xor(ssq, d, 64);
                    gw  += __shfl_xor(gw, d, 64);
                }
                if (p == 0) { red[bufi][i][h][0] = ssq; red[bufi][i][h][1] = gw; }
            }
        }
    };

    stage(0, 0);
    __syncthreads();
    for (int tl = 0; tl < CHUNK / 8; ++tl) {
        const int bufi = tl & 1;
        if (tl + 1 < CHUNK / 8) stage(tl + 1, bufi ^ 1);
        consume(tl, bufi);
        __syncthreads();
        if constexpr (FINAL) {
            if (tid < 8) {
                const size_t tok = row0 + tbase + tl * 8 + tid;
                const float ssq = red[bufi][tid][0][0] + red[bufi][tid][1][0]
                                + red[bufi][tid][2][0] + red[bufi][tid][3][0];
                const float gw  = red[bufi][tid][0][1] + red[bufi][tid][1][1]
                                + red[bufi][tid][2][1] + red[bufi][tid][3][1];
                const float rms = rsqrtf(ssq * (1.f / DINNER) + 1e-5f);
                rmsbuf[tok] = rms;
                values[tok] = gw * rms + bval[0];
            }
        }
    }

    if constexpr (!FINAL) {
#pragma unroll
        for (int n4 = 0; n4 < 16; ++n4)
            *(float4*)(states + stoff + n4 * 4) =
                make_float4(s[n4 * 4 + 0], s[n4 * 4 + 1], s[n4 * 4 + 2], s[n4 * 4 + 3]);
        if (p == 0) dAprod[bh * NCHUNK + ch] = dAp;
    }
}

// ---------------------------------------------------------------------------
// Inter-chunk state recurrence (in place): one thread per (bh, state element).
// ---------------------------------------------------------------------------
__global__ void chunk_scan(float* __restrict__ states, const float* __restrict__ dAprod)
{
    __shared__ float sdA[NCHUNK];
    const int bh = blockIdx.x >> 4;                       // 16 blocks per bh
    const int elem = ((blockIdx.x & 15) << 8) | threadIdx.x;
    if (threadIdx.x < NCHUNK) sdA[threadIdx.x] = dAprod[bh * NCHUNK + threadIdx.x];
    __syncthreads();
    const size_t base = (size_t)bh * NCHUNK * 4096 + elem;
    float s0 = 0.f;
    for (int c = 0; c < NCHUNK; ++c) {
        const size_t off = base + (size_t)c * 4096;
        const float Sc = states[off];
        states[off] = s0;
        s0 = fmaf(sdA[c], s0, Sc);
    }
}

// ---------------------------------------------------------------------------
extern "C" void kernel_launch(void* const* d_in, const int* in_sizes, int n_in,
                              void* d_out, int out_size, void* d_ws, size_t ws_size,
                              hipStream_t stream)
{
    (void)in_sizes; (void)n_in; (void)out_size; (void)ws_size;
    const float* obs     = (const float*)d_in[0];
    const float* W_enc   = (const float*)d_in[1];
    const float* b_enc   = (const float*)d_in[2];
    const float* W_in    = (const float*)d_in[3];
    const float* W_conv  = (const float*)d_in[4];
    const float* b_conv  = (const float*)d_in[5];
    const float* dt_bias = (const float*)d_in[6];
    const float* A_log   = (const float*)d_in[7];
    const float* Dp      = (const float*)d_in[8];
    const float* norm_w  = (const float*)d_in[9];
    const float* W_out   = (const float*)d_in[10];
    const float* W_act   = (const float*)d_in[11];
    const float* b_act   = (const float*)d_in[12];
    const float* W_val   = (const float*)d_in[13];
    const float* b_val   = (const float*)d_in[14];

    float* logits = (float*)d_out;
    float* values = logits + (size_t)NTOK * NACT;

    char* ws = (char*)d_ws;
    size_t off = 0;
    auto alloc = [&](size_t nfloats) {
        float* ptr = (float*)(ws + off);
        off += ((nfloats * 4 + 255) / 256) * 256;
        return ptr;
    };
    // ws high-water: 134.2+134.2+67.1+2.1 +67.1+67.1 + ~5 = ~477 MB (510 proven safe)
    float* zbuf   = alloc((size_t)NTOK * DINNER);                   // 134.2 MB (z -> g)
    float* xbuf   = alloc((size_t)NTOK * DINNER);                   // 134.2 MB
    float* bcbuf  = alloc((size_t)NTOK * BCW2);                     //  67.1 MB
    float* dtcol  = alloc((size_t)NTOK * 4);                        //   2.1 MB
    float* hidden = alloc((size_t)NTOK * DMODEL);                   //  67.1 MB
    float* states = alloc((size_t)NBATCH * NHEADS * NCHUNK * 4096); //  67.1 MB
    float* dAp    = alloc(NBATCH * NHEADS * NCHUNK);
    float* dtbuf  = alloc((size_t)NTOK * NHEADS);
    float* dAbuf  = alloc((size_t)NTOK * NHEADS);
    float* rmsbuf = alloc(NTOK);
    float* Wh     = alloc(DINNER * NACT);
    float* Wv     = alloc(DINNER);

    // 1. fused head weights
    fuse_whead<<<DINNER, NACT, 0, stream>>>(W_out, W_act, W_val, norm_w, Wh, Wv);
    // 2. hidden = obs @ W_enc + b_enc
    gemm_rrr<128, 64, 16><<<dim3(DMODEL / 64, NTOK / 128), 256, 0, stream>>>(
        obs, W_enc, hidden, NTOK, DMODEL, OBSD, OBSD, b_enc, nullptr);
    // 3. segmented in_proj: hidden @ W_in -> zbuf | xbuf | bcbuf | dtcol
    gemm_inproj<128, 64, 16><<<dim3((NPROJ + 63) / 64, NTOK / 128), 256, 0, stream>>>(
        hidden, W_in, NTOK, NPROJ, DMODEL, DMODEL, zbuf, xbuf, bcbuf, dtcol);
    // 4. dt / dA
    prep_dt<<<(NTOK * NHEADS + 255) / 256, 256, 0, stream>>>(dtcol, dt_bias, A_log, dtbuf, dAbuf);
    // 5. phase 1: chunk states
    scan_kernel<false><<<dim3(NCHUNK, NBATCH), 256, 0, stream>>>(
        xbuf, bcbuf, zbuf, dtbuf, dAbuf, W_conv, b_conv, Dp, states, dAp,
        nullptr, nullptr, nullptr, nullptr);
    // 6. phase 2: inter-chunk recurrence
    chunk_scan<<<NBATCH * NHEADS * 16, 256, 0, stream>>>(states, dAp);
    // 7. phase 3: outputs (g -> zbuf in place, rms, values)
    scan_kernel<true><<<dim3(NCHUNK, NBATCH), 256, 0, stream>>>(
        xbuf, bcbuf, zbuf, dtbuf, dAbuf, W_conv, b_conv, Dp, states, dAp,
        rmsbuf, Wv, b_val, values);
    // 8. logits = rms * (g @ Wh) + b_act   (A = zbuf dense, lda = 256)
    gemm_rrr<128, 64, 16><<<dim3(1, NTOK / 128), 256, 0, stream>>>(
        zbuf, Wh, logits, NTOK, NACT, DINNER, DINNER, b_act, rmsbuf);
}